// Round 1
// baseline (534.701 us; speedup 1.0000x reference)
//
#include <hip/hip_runtime.h>

#define NB 16384
#define NH 50
#define NITEMS 100000

// ws layout (floats):
//   fused_emb : [0, 6400000)            25.6 MB
//   user_vec  : [6400000, 7448576)       4.2 MB
//   target_rep: [7448576, 8497152)       4.2 MB

// ---------------- kernel A: fused_emb = embed_table @ fusion_w[0:64] ----------------
__global__ __launch_bounds__(256) void fuse_emb_k(
    const float* __restrict__ table, const float* __restrict__ fw,
    float* __restrict__ fused)
{
  __shared__ alignas(16) float srow[4][64];
  const int t  = threadIdx.x & 63;
  const int wv = threadIdx.x >> 6;
  const int waveG  = (blockIdx.x << 2) + wv;
  const int nwaves = gridDim.x << 2;
  float wcol[64];
#pragma unroll
  for (int k = 0; k < 64; ++k) wcol[k] = fw[k * 64 + t];  // emb rows of fusion_w, column t
  for (int item = waveG; item < NITEMS; item += nwaves) {
    srow[wv][t] = table[item * 64 + t];
    float a0 = 0.f, a1 = 0.f, a2 = 0.f, a3 = 0.f;
#pragma unroll
    for (int k4 = 0; k4 < 16; ++k4) {
      float4 x = *reinterpret_cast<const float4*>(&srow[wv][k4 * 4]);  // wave-uniform broadcast
      a0 = fmaf(x.x, wcol[4 * k4 + 0], a0);
      a1 = fmaf(x.y, wcol[4 * k4 + 1], a1);
      a2 = fmaf(x.z, wcol[4 * k4 + 2], a2);
      a3 = fmaf(x.w, wcol[4 * k4 + 3], a3);
    }
    fused[item * 64 + t] = (a0 + a1) + (a2 + a3);
  }
}

// ---------------- kernel B: history pooling + target rep ----------------
__global__ __launch_bounds__(256) void user_pool_k(
    const int* __restrict__ hidx, const float* __restrict__ hfeat,
    const float* __restrict__ hrat, const int* __restrict__ tidx,
    const float* __restrict__ tfeat, const float* __restrict__ fw,
    const float* __restrict__ fb, const float* __restrict__ fused,
    float* __restrict__ user_vec, float* __restrict__ target_rep)
{
  __shared__ alignas(16) float srow[4][64];
  const int t  = threadIdx.x & 63;
  const int wv = threadIdx.x >> 6;
  const int waveG  = (blockIdx.x << 2) + wv;
  const int nwaves = gridDim.x << 2;
  float wcol[64];
#pragma unroll
  for (int k = 0; k < 64; ++k) wcol[k] = fw[(64 + k) * 64 + t];  // feat rows, column t
  const float bias_t = fb[t];
  for (int b = waveG; b < NB; b += nwaves) {
    float uacc = 0.f, denom = 0.f;
    for (int h = 0; h < NH; ++h) {
      const int   idx = hidx[b * NH + h];                 // uniform -> s_load
      const float rw  = hrat[b * NH + h] - 3.0f;          // uniform
      const float emb_t = fused[idx * 64 + t];            // gather, issued early
      srow[wv][t] = hfeat[(b * NH + h) * 64 + t];
      float a0 = 0.f, a1 = 0.f, a2 = 0.f, a3 = 0.f;
#pragma unroll
      for (int k4 = 0; k4 < 16; ++k4) {
        float4 x = *reinterpret_cast<const float4*>(&srow[wv][k4 * 4]);
        a0 = fmaf(x.x, wcol[4 * k4 + 0], a0);
        a1 = fmaf(x.y, wcol[4 * k4 + 1], a1);
        a2 = fmaf(x.z, wcol[4 * k4 + 2], a2);
        a3 = fmaf(x.w, wcol[4 * k4 + 3], a3);
      }
      const float rep = fmaxf(((a0 + a1) + (a2 + a3)) + emb_t + bias_t, 0.f);
      uacc  = fmaf(rw, rep, uacc);
      denom += fabsf(rw);
    }
    user_vec[b * 64 + t] = uacc / (denom + 1e-8f);

    // target representation (same pipeline, weight 1, no pooling)
    {
      const int   idx   = tidx[b];
      const float emb_t = fused[idx * 64 + t];
      srow[wv][t] = tfeat[b * 64 + t];
      float a0 = 0.f, a1 = 0.f, a2 = 0.f, a3 = 0.f;
#pragma unroll
      for (int k4 = 0; k4 < 16; ++k4) {
        float4 x = *reinterpret_cast<const float4*>(&srow[wv][k4 * 4]);
        a0 = fmaf(x.x, wcol[4 * k4 + 0], a0);
        a1 = fmaf(x.y, wcol[4 * k4 + 1], a1);
        a2 = fmaf(x.z, wcol[4 * k4 + 2], a2);
        a3 = fmaf(x.w, wcol[4 * k4 + 3], a3);
      }
      target_rep[b * 64 + t] = fmaxf(((a0 + a1) + (a2 + a3)) + emb_t + bias_t, 0.f);
    }
  }
}

// ---------------- kernel C: rating MLP ----------------
__global__ __launch_bounds__(256) void mlp_k(
    const float* __restrict__ user_vec, const float* __restrict__ target_rep,
    const float* __restrict__ w1, const float* __restrict__ b1,
    const float* __restrict__ w2, const float* __restrict__ b2,
    const float* __restrict__ w3, const float* __restrict__ b3,
    float* __restrict__ out)
{
  __shared__ alignas(16) float s_w1[128 * 64];  // 32 KB
  __shared__ alignas(16) float s_w2[64 * 32];   //  8 KB
  __shared__ float s_w3[32];
  __shared__ alignas(16) float s_x[4][128];
  __shared__ alignas(16) float s_h1[4][64];
  const int tid = threadIdx.x;
  for (int i = tid; i < 128 * 64; i += 256) s_w1[i] = w1[i];
  for (int i = tid; i < 64 * 32;  i += 256) s_w2[i] = w2[i];
  if (tid < 32) s_w3[tid] = w3[tid];
  __syncthreads();

  const int t  = tid & 63;
  const int wv = tid >> 6;
  const int nwaves = gridDim.x << 2;
  const float b1t = b1[t];
  const float bb3 = b3[0];
  const int n2 = t & 31;
  const float b2n = b2[n2];
  for (int b = (blockIdx.x << 2) + wv; b < NB; b += nwaves) {
    s_x[wv][t]      = user_vec[b * 64 + t];
    s_x[wv][64 + t] = target_rep[b * 64 + t];
    // h1 = relu(x @ w1 + b1), lane t owns column t
    float a0 = b1t, a1 = 0.f, a2 = 0.f, a3 = 0.f;
#pragma unroll
    for (int k4 = 0; k4 < 32; ++k4) {
      float4 x = *reinterpret_cast<const float4*>(&s_x[wv][k4 * 4]);
      a0 = fmaf(x.x, s_w1[(4 * k4 + 0) * 64 + t], a0);
      a1 = fmaf(x.y, s_w1[(4 * k4 + 1) * 64 + t], a1);
      a2 = fmaf(x.z, s_w1[(4 * k4 + 2) * 64 + t], a2);
      a3 = fmaf(x.w, s_w1[(4 * k4 + 3) * 64 + t], a3);
    }
    s_h1[wv][t] = fmaxf((a0 + a1) + (a2 + a3), 0.f);
    // h2 = relu(h1 @ w2 + b2); all lanes compute n = t&31 (upper half duplicates)
    float c0 = b2n, c1 = 0.f, c2 = 0.f, c3 = 0.f;
#pragma unroll
    for (int k4 = 0; k4 < 16; ++k4) {
      float4 x = *reinterpret_cast<const float4*>(&s_h1[wv][k4 * 4]);
      c0 = fmaf(x.x, s_w2[(4 * k4 + 0) * 32 + n2], c0);
      c1 = fmaf(x.y, s_w2[(4 * k4 + 1) * 32 + n2], c1);
      c2 = fmaf(x.z, s_w2[(4 * k4 + 2) * 32 + n2], c2);
      c3 = fmaf(x.w, s_w2[(4 * k4 + 3) * 32 + n2], c3);
    }
    const float h2 = fmaxf((c0 + c1) + (c2 + c3), 0.f);
    float p = (t < 32) ? h2 * s_w3[n2] : 0.f;
#pragma unroll
    for (int m = 32; m >= 1; m >>= 1) p += __shfl_xor(p, m, 64);
    if (t == 0) out[b] = p + bb3;
  }
}

extern "C" void kernel_launch(void* const* d_in, const int* in_sizes, int n_in,
                              void* d_out, int out_size, void* d_ws, size_t ws_size,
                              hipStream_t stream) {
  const int*   hidx  = (const int*)  d_in[0];
  const float* hfeat = (const float*)d_in[1];
  const float* hrat  = (const float*)d_in[2];
  const int*   tidx  = (const int*)  d_in[3];
  const float* tfeat = (const float*)d_in[4];
  const float* table = (const float*)d_in[5];
  const float* fw    = (const float*)d_in[6];
  const float* fb    = (const float*)d_in[7];
  const float* w1    = (const float*)d_in[8];
  const float* b1    = (const float*)d_in[9];
  const float* w2    = (const float*)d_in[10];
  const float* b2    = (const float*)d_in[11];
  const float* w3    = (const float*)d_in[12];
  const float* b3    = (const float*)d_in[13];
  float* out = (float*)d_out;
  float* ws  = (float*)d_ws;
  float* fused      = ws;
  float* user_vec   = ws + 6400000;
  float* target_rep = ws + 7448576;

  hipLaunchKernelGGL(fuse_emb_k, dim3(1024), dim3(256), 0, stream, table, fw, fused);
  hipLaunchKernelGGL(user_pool_k, dim3(1024), dim3(256), 0, stream,
                     hidx, hfeat, hrat, tidx, tfeat, fw, fb, fused, user_vec, target_rep);
  hipLaunchKernelGGL(mlp_k, dim3(512), dim3(256), 0, stream,
                     user_vec, target_rep, w1, b1, w2, b2, w3, b3, out);
}

// Round 2
// 290.915 us; speedup vs baseline: 1.8380x; 1.8380x over previous
//
#include <hip/hip_runtime.h>

#define NB 16384
#define NH 50
#define NITEMS 100000

// ws layout (floats):
//   fused_emb : [0, 6400000)            25.6 MB
//   user_vec  : [6400000, 7448576)       4.2 MB
//   target_rep: [7448576, 8497152)       4.2 MB

// ---------------- kernel A: fused_emb = embed_table @ fusion_w[0:64] ----------------
__global__ __launch_bounds__(256) void fuse_emb_k(
    const float* __restrict__ table, const float* __restrict__ fw,
    float* __restrict__ fused)
{
  __shared__ alignas(16) float srow[4][64];
  const int t  = threadIdx.x & 63;
  const int wv = threadIdx.x >> 6;
  const int waveG  = (blockIdx.x << 2) + wv;
  const int nwaves = gridDim.x << 2;
  float wcol[64];
#pragma unroll
  for (int k = 0; k < 64; ++k) wcol[k] = fw[k * 64 + t];
  for (int item = waveG; item < NITEMS; item += nwaves) {
    srow[wv][t] = table[(size_t)item * 64 + t];
    float a0 = 0.f, a1 = 0.f, a2 = 0.f, a3 = 0.f;
#pragma unroll
    for (int k4 = 0; k4 < 16; ++k4) {
      float4 x = *reinterpret_cast<const float4*>(&srow[wv][k4 * 4]);
      a0 = fmaf(x.x, wcol[4 * k4 + 0], a0);
      a1 = fmaf(x.y, wcol[4 * k4 + 1], a1);
      a2 = fmaf(x.z, wcol[4 * k4 + 2], a2);
      a3 = fmaf(x.w, wcol[4 * k4 + 3], a3);
    }
    fused[(size_t)item * 64 + t] = (a0 + a1) + (a2 + a3);
  }
}

// ---------------- kernel B: history pooling + target rep (pipelined) ----------------
__global__ __launch_bounds__(256) void user_pool_k(
    const int* __restrict__ hidx, const float* __restrict__ hfeat,
    const float* __restrict__ hrat, const int* __restrict__ tidx,
    const float* __restrict__ tfeat, const float* __restrict__ fw,
    const float* __restrict__ fb, const float* __restrict__ fused,
    float* __restrict__ user_vec, float* __restrict__ target_rep)
{
  __shared__ float4 sbuf[4][2][64];   // per-wave double buffer: 4 rows x 64 floats
  const int t  = threadIdx.x & 63;
  const int wv = threadIdx.x >> 6;
  const int wave0 = (blockIdx.x << 2) + wv;     // 0..8191
  float wcol[64];
#pragma unroll
  for (int k = 0; k < 64; ++k) wcol[k] = fw[(64 + k) * 64 + t];  // feat rows, column t
  const float bias_t = fb[t];
  const int hl = (t < NH) ? t : (NH - 1);
  float* const sp0 = (float*)&sbuf[wv][0][0];
  float* const sp1 = (float*)&sbuf[wv][1][0];

  for (int rep = 0; rep < 2; ++rep) {
    const int b = wave0 + (rep << 13);
    // all indices + ratings for this batch live in lane registers
    const int   ihv = hidx[b * NH + hl];
    const float rtv = hrat[b * NH + hl];
    const float4* hrow4 = (const float4*)(hfeat + (size_t)b * NH * 64);

    // prologue: stage rows 0..3 and gathers for h=0..3
    float4 fv = hrow4[t];
    float e0 = fused[(size_t)__shfl(ihv, 0) * 64 + t];
    float e1 = fused[(size_t)__shfl(ihv, 1) * 64 + t];
    float e2 = fused[(size_t)__shfl(ihv, 2) * 64 + t];
    float e3 = fused[(size_t)__shfl(ihv, 3) * 64 + t];

    float uacc = 0.f, den = 0.f;

#pragma unroll 2
    for (int it = 0; it < 12; ++it) {     // items 0..47, 4 per iteration
      float* sp = (it & 1) ? sp1 : sp0;
      ((float4*)sp)[t] = fv;
      // --- prefetch next iteration (rows/gathers for it+1; it==11 -> remainder 48,49) ---
      {
        int r = (it + 1) * 4 + (t >> 4);
        if (r > NH - 1) r = NH - 1;
        fv = hrow4[r * 16 + (t & 15)];
      }
      const int g = (it + 1) * 4;
      const int g1 = (g + 1 < NH) ? g + 1 : NH - 1;
      const int g2 = (g + 2 < NH) ? g + 2 : NH - 1;
      const int g3 = (g + 3 < NH) ? g + 3 : NH - 1;
      float n0 = fused[(size_t)__shfl(ihv, g)  * 64 + t];
      float n1 = fused[(size_t)__shfl(ihv, g1) * 64 + t];
      float n2 = fused[(size_t)__shfl(ihv, g2) * 64 + t];
      float n3 = fused[(size_t)__shfl(ihv, g3) * 64 + t];
      // --- compute current 4 items ---
#pragma unroll
      for (int j = 0; j < 4; ++j) {
        const int h = it * 4 + j;
        const float rw = __shfl(rtv, h) - 3.0f;
        const float ej = (j == 0) ? e0 : (j == 1) ? e1 : (j == 2) ? e2 : e3;
        float a0 = 0.f, a1 = 0.f, a2 = 0.f, a3 = 0.f;
#pragma unroll
        for (int k4 = 0; k4 < 16; ++k4) {
          float4 x = *reinterpret_cast<const float4*>(&sp[j * 64 + k4 * 4]);
          a0 = fmaf(x.x, wcol[4 * k4 + 0], a0);
          a1 = fmaf(x.y, wcol[4 * k4 + 1], a1);
          a2 = fmaf(x.z, wcol[4 * k4 + 2], a2);
          a3 = fmaf(x.w, wcol[4 * k4 + 3], a3);
        }
        const float rv = fmaxf((a0 + a1) + (a2 + a3) + ej + bias_t, 0.f);
        uacc = fmaf(rw, rv, uacc);
        den += fabsf(rw);
      }
      e0 = n0; e1 = n1; e2 = n2; e3 = n3;
    }

    // epilogue: items 48,49 (staged rows in fv, gathers in e0,e1)
    {
      ((float4*)sp0)[t] = fv;
#pragma unroll
      for (int j = 0; j < 2; ++j) {
        const int h = 48 + j;
        const float rw = __shfl(rtv, h) - 3.0f;
        const float ej = (j == 0) ? e0 : e1;
        float a0 = 0.f, a1 = 0.f, a2 = 0.f, a3 = 0.f;
#pragma unroll
        for (int k4 = 0; k4 < 16; ++k4) {
          float4 x = *reinterpret_cast<const float4*>(&sp0[j * 64 + k4 * 4]);
          a0 = fmaf(x.x, wcol[4 * k4 + 0], a0);
          a1 = fmaf(x.y, wcol[4 * k4 + 1], a1);
          a2 = fmaf(x.z, wcol[4 * k4 + 2], a2);
          a3 = fmaf(x.w, wcol[4 * k4 + 3], a3);
        }
        const float rv = fmaxf((a0 + a1) + (a2 + a3) + ej + bias_t, 0.f);
        uacc = fmaf(rw, rv, uacc);
        den += fabsf(rw);
      }
      user_vec[(size_t)b * 64 + t] = uacc / (den + 1e-8f);
    }

    // target representation
    {
      const int   ti = tidx[b];
      const float et = fused[(size_t)ti * 64 + t];
      sp1[t] = tfeat[(size_t)b * 64 + t];
      float a0 = 0.f, a1 = 0.f, a2 = 0.f, a3 = 0.f;
#pragma unroll
      for (int k4 = 0; k4 < 16; ++k4) {
        float4 x = *reinterpret_cast<const float4*>(&sp1[k4 * 4]);
        a0 = fmaf(x.x, wcol[4 * k4 + 0], a0);
        a1 = fmaf(x.y, wcol[4 * k4 + 1], a1);
        a2 = fmaf(x.z, wcol[4 * k4 + 2], a2);
        a3 = fmaf(x.w, wcol[4 * k4 + 3], a3);
      }
      target_rep[(size_t)b * 64 + t] = fmaxf((a0 + a1) + (a2 + a3) + et + bias_t, 0.f);
    }
  }
}

// ---------------- kernel C: rating MLP ----------------
__global__ __launch_bounds__(256) void mlp_k(
    const float* __restrict__ user_vec, const float* __restrict__ target_rep,
    const float* __restrict__ w1, const float* __restrict__ b1,
    const float* __restrict__ w2, const float* __restrict__ b2,
    const float* __restrict__ w3, const float* __restrict__ b3,
    float* __restrict__ out)
{
  __shared__ alignas(16) float s_w1[128 * 64];  // 32 KB
  __shared__ alignas(16) float s_w2[64 * 32];   //  8 KB
  __shared__ float s_w3[32];
  __shared__ alignas(16) float s_x[4][128];
  __shared__ alignas(16) float s_h1[4][64];
  const int tid = threadIdx.x;
  for (int i = tid; i < 128 * 64; i += 256) s_w1[i] = w1[i];
  for (int i = tid; i < 64 * 32;  i += 256) s_w2[i] = w2[i];
  if (tid < 32) s_w3[tid] = w3[tid];
  __syncthreads();

  const int t  = tid & 63;
  const int wv = tid >> 6;
  const int nwaves = gridDim.x << 2;
  const float b1t = b1[t];
  const float bb3 = b3[0];
  const int n2 = t & 31;
  const float b2n = b2[n2];
  for (int b = (blockIdx.x << 2) + wv; b < NB; b += nwaves) {
    s_x[wv][t]      = user_vec[(size_t)b * 64 + t];
    s_x[wv][64 + t] = target_rep[(size_t)b * 64 + t];
    float a0 = b1t, a1 = 0.f, a2 = 0.f, a3 = 0.f;
#pragma unroll
    for (int k4 = 0; k4 < 32; ++k4) {
      float4 x = *reinterpret_cast<const float4*>(&s_x[wv][k4 * 4]);
      a0 = fmaf(x.x, s_w1[(4 * k4 + 0) * 64 + t], a0);
      a1 = fmaf(x.y, s_w1[(4 * k4 + 1) * 64 + t], a1);
      a2 = fmaf(x.z, s_w1[(4 * k4 + 2) * 64 + t], a2);
      a3 = fmaf(x.w, s_w1[(4 * k4 + 3) * 64 + t], a3);
    }
    s_h1[wv][t] = fmaxf((a0 + a1) + (a2 + a3), 0.f);
    float c0 = b2n, c1 = 0.f, c2 = 0.f, c3 = 0.f;
#pragma unroll
    for (int k4 = 0; k4 < 16; ++k4) {
      float4 x = *reinterpret_cast<const float4*>(&s_h1[wv][k4 * 4]);
      c0 = fmaf(x.x, s_w2[(4 * k4 + 0) * 32 + n2], c0);
      c1 = fmaf(x.y, s_w2[(4 * k4 + 1) * 32 + n2], c1);
      c2 = fmaf(x.z, s_w2[(4 * k4 + 2) * 32 + n2], c2);
      c3 = fmaf(x.w, s_w2[(4 * k4 + 3) * 32 + n2], c3);
    }
    const float h2 = fmaxf((c0 + c1) + (c2 + c3), 0.f);
    float p = (t < 32) ? h2 * s_w3[n2] : 0.f;
#pragma unroll
    for (int m = 32; m >= 1; m >>= 1) p += __shfl_xor(p, m, 64);
    if (t == 0) out[b] = p + bb3;
  }
}

extern "C" void kernel_launch(void* const* d_in, const int* in_sizes, int n_in,
                              void* d_out, int out_size, void* d_ws, size_t ws_size,
                              hipStream_t stream) {
  const int*   hidx  = (const int*)  d_in[0];
  const float* hfeat = (const float*)d_in[1];
  const float* hrat  = (const float*)d_in[2];
  const int*   tidx  = (const int*)  d_in[3];
  const float* tfeat = (const float*)d_in[4];
  const float* table = (const float*)d_in[5];
  const float* fw    = (const float*)d_in[6];
  const float* fb    = (const float*)d_in[7];
  const float* w1    = (const float*)d_in[8];
  const float* b1    = (const float*)d_in[9];
  const float* w2    = (const float*)d_in[10];
  const float* b2    = (const float*)d_in[11];
  const float* w3    = (const float*)d_in[12];
  const float* b3    = (const float*)d_in[13];
  float* out = (float*)d_out;
  float* ws  = (float*)d_ws;
  float* fused      = ws;
  float* user_vec   = ws + 6400000;
  float* target_rep = ws + 7448576;

  hipLaunchKernelGGL(fuse_emb_k, dim3(1024), dim3(256), 0, stream, table, fw, fused);
  hipLaunchKernelGGL(user_pool_k, dim3(2048), dim3(256), 0, stream,
                     hidx, hfeat, hrat, tidx, tfeat, fw, fb, fused, user_vec, target_rep);
  hipLaunchKernelGGL(mlp_k, dim3(512), dim3(256), 0, stream,
                     user_vec, target_rep, w1, b1, w2, b2, w3, b3, out);
}

// Round 4
// 256.840 us; speedup vs baseline: 2.0818x; 1.1327x over previous
//
#include <hip/hip_runtime.h>

#define NB 16384
#define NH 50
#define NITEMS 100000

typedef __attribute__((ext_vector_type(16))) float f32x16;
typedef __attribute__((ext_vector_type(8)))  float f32x8;
typedef __attribute__((ext_vector_type(8)))  int   i32x8;

// ws layout (floats):
//   fused_emb : [0, 6400000)            25.6 MB
//   user_vec  : [6400000, 7448576)       4.2 MB
//   target_rep: [7448576, 8497152)       4.2 MB

// Load one wave-uniform 256B row into 64 SGPRs and dot it against the
// per-lane weight column held in 64 VGPRs. 4 independent FMA chains.
#define ROW_FMA(RA, SUM)                                                      \
  float SUM;                                                                  \
  {                                                                           \
    f32x16 r0_, r1_, r2_, r3_;                                                \
    asm volatile("s_load_dwordx16 %0, %4, 0x0\n\t"                            \
                 "s_load_dwordx16 %1, %4, 0x40\n\t"                           \
                 "s_load_dwordx16 %2, %4, 0x80\n\t"                           \
                 "s_load_dwordx16 %3, %4, 0xc0"                               \
                 : "=&s"(r0_), "=&s"(r1_), "=&s"(r2_), "=&s"(r3_)             \
                 : "s"(RA));                                                  \
    asm volatile("s_waitcnt lgkmcnt(0)"                                       \
                 : "+s"(r0_), "+s"(r1_), "+s"(r2_), "+s"(r3_));               \
    float a0_ = 0.f, a1_ = 0.f, a2_ = 0.f, a3_ = 0.f;                         \
    _Pragma("unroll") for (int k_ = 0; k_ < 16; ++k_) {                       \
      a0_ = fmaf(r0_[k_], wcol[k_],      a0_);                                \
      a1_ = fmaf(r1_[k_], wcol[16 + k_], a1_);                                \
      a2_ = fmaf(r2_[k_], wcol[32 + k_], a2_);                                \
      a3_ = fmaf(r3_[k_], wcol[48 + k_], a3_);                                \
    }                                                                         \
    SUM = (a0_ + a1_) + (a2_ + a3_);                                          \
  }

// ---------------- kernel A: fused_emb = embed_table @ fusion_w[0:64] ----------------
__global__ __launch_bounds__(256) void fuse_emb_k(
    const float* __restrict__ table, const float* __restrict__ fw,
    float* __restrict__ fused)
{
  const int t   = threadIdx.x & 63;
  const int wvu = __builtin_amdgcn_readfirstlane(threadIdx.x >> 6);
  const int waveG  = (blockIdx.x << 2) + wvu;
  const int nwaves = gridDim.x << 2;
  float wcol[64];
#pragma unroll
  for (int k = 0; k < 64; ++k) wcol[k] = fw[k * 64 + t];
  const uint64_t tab_u = (uint64_t)table;
  for (int item = waveG; item < NITEMS; item += nwaves) {
    const uint64_t ra = tab_u + (uint64_t)item * 256u;
    ROW_FMA(ra, s);
    fused[(size_t)item * 64 + t] = s;
  }
}

// ---------------- kernel B: history pooling + target rep (SGPR rows) ----------------
#define HDR(GI, RN, OFFB)                                                     \
  asm volatile("s_load_dwordx8 %0, %2, 0x0\n\t"                               \
               "s_load_dwordx8 %1, %3, 0x0"                                   \
               : "=&s"(GI), "=&s"(RN)                                         \
               : "s"(hidxb + (uint64_t)(OFFB)), "s"(hratb + (uint64_t)(OFFB)));\
  asm volatile("s_waitcnt lgkmcnt(0)" : "+s"(GI), "+s"(RN));

#define GATHER8(E, GI)                                                        \
  _Pragma("unroll") for (int q = 0; q < 8; ++q) {                             \
    E[q] = fused[((size_t)(int)GI[q] << 6) + t];                              \
  }

#define ITEM8(ECUR, RCUR, GBASE)                                              \
  _Pragma("unroll") for (int j = 0; j < 8; ++j) {                             \
    const uint64_t ra_ = (GBASE) + (uint64_t)(j * 256);                       \
    ROW_FMA(ra_, s_);                                                         \
    const float rv_ = fmaxf(s_ + ECUR[j] + bias_t, 0.f);                      \
    const float rw_ = RCUR[j] - 3.0f;                                         \
    uacc = fmaf(rw_, rv_, uacc);                                              \
    den += fabsf(rw_);                                                        \
  }

#define GROUP(ECUR, ENXT, RCUR, RNXT, G)                                      \
  {                                                                           \
    const int offb_ = (((G) < 5) ? ((G) + 1) * 8 : 42) * 4;                   \
    i32x8 gin_;                                                               \
    HDR(gin_, RNXT, offb_);                                                   \
    GATHER8(ENXT, gin_);                                                      \
    ITEM8(ECUR, RCUR, hfb + (uint64_t)((G) * 2048));                          \
  }

__global__ __launch_bounds__(256) void user_pool_k(
    const int* __restrict__ hidx, const float* __restrict__ hfeat,
    const float* __restrict__ hrat, const int* __restrict__ tidx,
    const float* __restrict__ tfeat, const float* __restrict__ fw,
    const float* __restrict__ fb, const float* __restrict__ fused,
    float* __restrict__ user_vec, float* __restrict__ target_rep)
{
  const int t   = threadIdx.x & 63;
  const int wvu = __builtin_amdgcn_readfirstlane(threadIdx.x >> 6);
  const int b   = (blockIdx.x << 2) + wvu;   // one batch per wave, grid 4096
  float wcol[64];
#pragma unroll
  for (int k = 0; k < 64; ++k) wcol[k] = fw[(64 + k) * 64 + t];  // feat rows, col t
  const float bias_t = fb[t];

  const uint64_t hfb   = (uint64_t)hfeat + (uint64_t)b * 12800u;  // 50*256B
  const uint64_t hidxb = (uint64_t)hidx  + (uint64_t)b * 200u;    // 50*4B
  const uint64_t hratb = (uint64_t)hrat  + (uint64_t)b * 200u;

  // prologue: header for group 0, its gathers, and the target gather
  i32x8 g0_;
  f32x8 ratA, ratB;
  HDR(g0_, ratA, 0);
  float eA[8], eB[8];
  GATHER8(eA, g0_);
  const int   ti  = tidx[b];
  const float etg = fused[((size_t)ti << 6) + t];

  float uacc = 0.f, den = 0.f;
  GROUP(eA, eB, ratA, ratB, 0);
  GROUP(eB, eA, ratB, ratA, 1);
  GROUP(eA, eB, ratA, ratB, 2);
  GROUP(eB, eA, ratB, ratA, 3);
  GROUP(eA, eB, ratA, ratB, 4);
  GROUP(eB, eA, ratB, ratA, 5);
  // after group 5: eA/ratA hold the window for items 42..49; tail = elems 6,7
#pragma unroll
  for (int jj = 6; jj < 8; ++jj) {
    const uint64_t ra = hfb + (uint64_t)((42 + jj) * 256);
    ROW_FMA(ra, s_);
    const float rv = fmaxf(s_ + eA[jj] + bias_t, 0.f);
    const float rw = ratA[jj] - 3.0f;
    uacc = fmaf(rw, rv, uacc);
    den += fabsf(rw);
  }
  user_vec[(size_t)b * 64 + t] = uacc / (den + 1e-8f);

  // target representation
  {
    const uint64_t ra = (uint64_t)tfeat + (uint64_t)b * 256u;
    ROW_FMA(ra, ts_);
    target_rep[(size_t)b * 64 + t] = fmaxf(ts_ + etg + bias_t, 0.f);
  }
}

// ---------------- kernel C: rating MLP ----------------
__global__ __launch_bounds__(256) void mlp_k(
    const float* __restrict__ user_vec, const float* __restrict__ target_rep,
    const float* __restrict__ w1, const float* __restrict__ b1,
    const float* __restrict__ w2, const float* __restrict__ b2,
    const float* __restrict__ w3, const float* __restrict__ b3,
    float* __restrict__ out)
{
  __shared__ alignas(16) float s_w1[128 * 64];  // 32 KB
  __shared__ alignas(16) float s_w2[64 * 32];   //  8 KB
  __shared__ float s_w3[32];
  __shared__ alignas(16) float s_x[4][128];
  __shared__ alignas(16) float s_h1[4][64];
  const int tid = threadIdx.x;
  for (int i = tid; i < 128 * 64; i += 256) s_w1[i] = w1[i];
  for (int i = tid; i < 64 * 32;  i += 256) s_w2[i] = w2[i];
  if (tid < 32) s_w3[tid] = w3[tid];
  __syncthreads();

  const int t  = tid & 63;
  const int wv = tid >> 6;
  const int nwaves = gridDim.x << 2;
  const float b1t = b1[t];
  const float bb3 = b3[0];
  const int n2 = t & 31;
  const float b2n = b2[n2];
  for (int b = (blockIdx.x << 2) + wv; b < NB; b += nwaves) {
    s_x[wv][t]      = user_vec[(size_t)b * 64 + t];
    s_x[wv][64 + t] = target_rep[(size_t)b * 64 + t];
    float a0 = b1t, a1 = 0.f, a2 = 0.f, a3 = 0.f;
#pragma unroll
    for (int k4 = 0; k4 < 32; ++k4) {
      float4 x = *reinterpret_cast<const float4*>(&s_x[wv][k4 * 4]);
      a0 = fmaf(x.x, s_w1[(4 * k4 + 0) * 64 + t], a0);
      a1 = fmaf(x.y, s_w1[(4 * k4 + 1) * 64 + t], a1);
      a2 = fmaf(x.z, s_w1[(4 * k4 + 2) * 64 + t], a2);
      a3 = fmaf(x.w, s_w1[(4 * k4 + 3) * 64 + t], a3);
    }
    s_h1[wv][t] = fmaxf((a0 + a1) + (a2 + a3), 0.f);
    float c0 = b2n, c1 = 0.f, c2 = 0.f, c3 = 0.f;
#pragma unroll
    for (int k4 = 0; k4 < 16; ++k4) {
      float4 x = *reinterpret_cast<const float4*>(&s_h1[wv][k4 * 4]);
      c0 = fmaf(x.x, s_w2[(4 * k4 + 0) * 32 + n2], c0);
      c1 = fmaf(x.y, s_w2[(4 * k4 + 1) * 32 + n2], c1);
      c2 = fmaf(x.z, s_w2[(4 * k4 + 2) * 32 + n2], c2);
      c3 = fmaf(x.w, s_w2[(4 * k4 + 3) * 32 + n2], c3);
    }
    const float h2 = fmaxf((c0 + c1) + (c2 + c3), 0.f);
    float p = (t < 32) ? h2 * s_w3[n2] : 0.f;
#pragma unroll
    for (int m = 32; m >= 1; m >>= 1) p += __shfl_xor(p, m, 64);
    if (t == 0) out[b] = p + bb3;
  }
}

extern "C" void kernel_launch(void* const* d_in, const int* in_sizes, int n_in,
                              void* d_out, int out_size, void* d_ws, size_t ws_size,
                              hipStream_t stream) {
  const int*   hidx  = (const int*)  d_in[0];
  const float* hfeat = (const float*)d_in[1];
  const float* hrat  = (const float*)d_in[2];
  const int*   tidx  = (const int*)  d_in[3];
  const float* tfeat = (const float*)d_in[4];
  const float* table = (const float*)d_in[5];
  const float* fw    = (const float*)d_in[6];
  const float* fb    = (const float*)d_in[7];
  const float* w1    = (const float*)d_in[8];
  const float* b1    = (const float*)d_in[9];
  const float* w2    = (const float*)d_in[10];
  const float* b2    = (const float*)d_in[11];
  const float* w3    = (const float*)d_in[12];
  const float* b3    = (const float*)d_in[13];
  float* out = (float*)d_out;
  float* ws  = (float*)d_ws;
  float* fused      = ws;
  float* user_vec   = ws + 6400000;
  float* target_rep = ws + 7448576;

  hipLaunchKernelGGL(fuse_emb_k, dim3(6250), dim3(256), 0, stream, table, fw, fused);
  hipLaunchKernelGGL(user_pool_k, dim3(4096), dim3(256), 0, stream,
                     hidx, hfeat, hrat, tidx, tfeat, fw, fb, fused, user_vec, target_rep);
  hipLaunchKernelGGL(mlp_k, dim3(512), dim3(256), 0, stream,
                     user_vec, target_rep, w1, b1, w2, b2, w3, b3, out);
}

// Round 5
// 132.622 us; speedup vs baseline: 4.0318x; 1.9366x over previous
//
#include <hip/hip_runtime.h>

#define NB 16384
#define NH 50

typedef __attribute__((ext_vector_type(4))) float        f32x4;
typedef __attribute__((ext_vector_type(8))) short        s16x8;
typedef __attribute__((ext_vector_type(4))) unsigned int u32x4;

// ws layout (floats):
//   bfrag (u32) : [0, 8192)        32 KB  — W hi/lo bf16 MFMA fragments
//   user_vec    : [6400000, +1M)   4.2 MB
//   target_rep  : [7448576, +1M)   4.2 MB

__device__ __forceinline__ unsigned rne16(float x) {
  unsigned u = __float_as_uint(x);
  return (u + 0x7FFFu + ((u >> 16) & 1u)) >> 16;
}
__device__ __forceinline__ unsigned pack_hi(float x0, float x1, float& r0, float& r1) {
  const unsigned h0 = rne16(x0), h1 = rne16(x1);
  r0 = x0 - __uint_as_float(h0 << 16);
  r1 = x1 - __uint_as_float(h1 << 16);
  return h0 | (h1 << 16);
}
__device__ __forceinline__ unsigned pack_rne(float x0, float x1) {
  return rne16(x0) | (rne16(x1) << 16);
}
__device__ __forceinline__ void cvt8(const f32x4 a, const f32x4 b, u32x4& hi, u32x4& lo) {
  float r0, r1;
  hi[0] = pack_hi(a[0], a[1], r0, r1); lo[0] = pack_rne(r0, r1);
  hi[1] = pack_hi(a[2], a[3], r0, r1); lo[1] = pack_rne(r0, r1);
  hi[2] = pack_hi(b[0], b[1], r0, r1); lo[2] = pack_rne(r0, r1);
  hi[3] = pack_hi(b[2], b[3], r0, r1); lo[3] = pack_rne(r0, r1);
}

// ---------------- kernel W: build bf16 hi/lo B-fragments of fusion_w ----------------
// frag set f = (ks<<3)|(nt<<1)|sp ; lane l ; dword j : B[ks*32+(l>>4)*8+2j(+1)][nt*16+(l&15)]
__global__ __launch_bounds__(256) void wprep_k(const float* __restrict__ fw,
                                               unsigned* __restrict__ bfrag) {
  const int d = blockIdx.x * 256 + threadIdx.x;   // 0..8191
  const int j = d & 3, l = (d >> 2) & 63, f = d >> 8;
  const int sp = f & 1, nt = (f >> 1) & 3, ks = f >> 3;
  const int n  = nt * 16 + (l & 15);
  const int k0 = ks * 32 + (l >> 4) * 8 + 2 * j;
  const float w0 = fw[k0 * 64 + n], w1 = fw[(k0 + 1) * 64 + n];
  const unsigned h0 = rne16(w0), h1 = rne16(w1);
  unsigned dw;
  if (sp == 0) dw = h0 | (h1 << 16);
  else {
    const float r0 = w0 - __uint_as_float(h0 << 16);
    const float r1 = w1 - __uint_as_float(h1 << 16);
    dw = rne16(r0) | (rne16(r1) << 16);
  }
  bfrag[d] = dw;
}

// ---------------- kernel B: MFMA item-rep + pooling, one batch per wave ----------------
__global__ __launch_bounds__(256, 2) void pool_mfma_k(
    const int* __restrict__ hidx, const float* __restrict__ hfeat,
    const float* __restrict__ hrat, const int* __restrict__ tidx,
    const float* __restrict__ tfeat, const float* __restrict__ table,
    const float* __restrict__ fb, const unsigned* __restrict__ bfrag,
    float* __restrict__ user_vec, float* __restrict__ target_rep)
{
  const int l  = threadIdx.x & 63;
  const int wv = threadIdx.x >> 6;
  const int wave = (blockIdx.x << 2) + wv;          // 0..2047
  const int lm = l & 15, lg = l >> 4;

  // W fragments resident in VGPRs for the wave lifetime
  u32x4 B[4][4][2];
#pragma unroll
  for (int ks = 0; ks < 4; ++ks)
#pragma unroll
    for (int nt = 0; nt < 4; ++nt)
#pragma unroll
      for (int sp = 0; sp < 2; ++sp) {
        const int f = (ks << 3) | (nt << 1) | sp;
        B[ks][nt][sp] = *(const u32x4*)(bfrag + ((size_t)f * 64 + l) * 4);
      }
  float bias[4];
#pragma unroll
  for (int nt = 0; nt < 4; ++nt) bias[nt] = fb[nt * 16 + lm];

  for (int b = wave; b < NB; b += 2048) {
    // ratings -> lane regs; weights w_r = rat-3 for r<50, 0 for target/pad rows
    float rw_all = 0.f;
    if (l < NH) rw_all = hrat[(size_t)b * NH + l] - 3.0f;
    float den = fabsf(rw_all);
#pragma unroll
    for (int s = 32; s >= 1; s >>= 1) den += __shfl_xor(den, s, 64);

    float uacc[4] = {0.f, 0.f, 0.f, 0.f};
    float trep[4] = {0.f, 0.f, 0.f, 0.f};

#pragma unroll
    for (int m = 0; m < 4; ++m) {
      const int r = m * 16 + lm;                    // A-row this lane loads
      const int* ip = (r < NH) ? (hidx + (size_t)b * NH + r)
                    : (r == NH) ? (tidx + b)
                                : (hidx + (size_t)b * NH + (NH - 1));
      const float* fp = (r < NH) ? (hfeat + ((size_t)b * NH + r) * 64)
                      : (r == NH) ? (tfeat + (size_t)b * 64)
                                  : (hfeat + ((size_t)b * NH + (NH - 1)) * 64);
      const int idxv = *ip;
      const float* ep = table + (size_t)idxv * 64;
      // A cols: 0..63 = emb (gathered), 64..127 = feat ; lane holds 8 consecutive k per kstep
      f32x4 q0 = *(const f32x4*)(ep + lg * 8);
      f32x4 q1 = *(const f32x4*)(ep + lg * 8 + 4);
      f32x4 q2 = *(const f32x4*)(ep + 32 + lg * 8);
      f32x4 q3 = *(const f32x4*)(ep + 32 + lg * 8 + 4);
      f32x4 q4 = *(const f32x4*)(fp + lg * 8);
      f32x4 q5 = *(const f32x4*)(fp + lg * 8 + 4);
      f32x4 q6 = *(const f32x4*)(fp + 32 + lg * 8);
      f32x4 q7 = *(const f32x4*)(fp + 32 + lg * 8 + 4);
      u32x4 ahi[4], alo[4];
      cvt8(q0, q1, ahi[0], alo[0]);
      cvt8(q2, q3, ahi[1], alo[1]);
      cvt8(q4, q5, ahi[2], alo[2]);
      cvt8(q6, q7, ahi[3], alo[3]);

      f32x4 acc[4];
#pragma unroll
      for (int nt = 0; nt < 4; ++nt) {
        const float bv = bias[nt];
        acc[nt] = (f32x4){bv, bv, bv, bv};
      }
#pragma unroll
      for (int ks = 0; ks < 4; ++ks) {
        const s16x8 ah = __builtin_bit_cast(s16x8, ahi[ks]);
        const s16x8 al = __builtin_bit_cast(s16x8, alo[ks]);
#pragma unroll
        for (int nt = 0; nt < 4; ++nt) {
          const s16x8 bh = __builtin_bit_cast(s16x8, B[ks][nt][0]);
          const s16x8 bl = __builtin_bit_cast(s16x8, B[ks][nt][1]);
          acc[nt] = __builtin_amdgcn_mfma_f32_16x16x32_bf16(ah, bh, acc[nt], 0, 0, 0);
          acc[nt] = __builtin_amdgcn_mfma_f32_16x16x32_bf16(al, bh, acc[nt], 0, 0, 0);
          acc[nt] = __builtin_amdgcn_mfma_f32_16x16x32_bf16(ah, bl, acc[nt], 0, 0, 0);
        }
      }
      // epilogue: relu + weighted pooling ; C layout: col=lm+16nt, row=m*16+lg*4+e
#pragma unroll
      for (int nt = 0; nt < 4; ++nt) {
#pragma unroll
        for (int e = 0; e < 4; ++e) {
          const float rep = fmaxf(acc[nt][e], 0.f);
          const int   rr  = m * 16 + lg * 4 + e;
          const float w   = __shfl(rw_all, rr, 64);
          uacc[nt] = fmaf(w, rep, uacc[nt]);
          if (m == 3 && e == 2) trep[nt] = rep;   // row 50 = target (valid on lg==0)
        }
      }
    }

    // reduce over the 4 row-groups, then lane l writes col l
#pragma unroll
    for (int nt = 0; nt < 4; ++nt) {
      uacc[nt] += __shfl_xor(uacc[nt], 16, 64);
      uacc[nt] += __shfl_xor(uacc[nt], 32, 64);
    }
    const float dinv = den + 1e-8f;
    const float usel = (lg == 0) ? uacc[0] : (lg == 1) ? uacc[1]
                     : (lg == 2) ? uacc[2] : uacc[3];
    user_vec[(size_t)b * 64 + l] = usel / dinv;
    if (l < 16) {
      float* tp = target_rep + (size_t)b * 64 + l;
      tp[0]  = trep[0];
      tp[16] = trep[1];
      tp[32] = trep[2];
      tp[48] = trep[3];
    }
  }
}

// ---------------- kernel C: rating MLP ----------------
__global__ __launch_bounds__(256) void mlp_k(
    const float* __restrict__ user_vec, const float* __restrict__ target_rep,
    const float* __restrict__ w1, const float* __restrict__ b1,
    const float* __restrict__ w2, const float* __restrict__ b2,
    const float* __restrict__ w3, const float* __restrict__ b3,
    float* __restrict__ out)
{
  __shared__ alignas(16) float s_w1[128 * 64];  // 32 KB
  __shared__ alignas(16) float s_w2[64 * 32];   //  8 KB
  __shared__ float s_w3[32];
  __shared__ alignas(16) float s_x[4][128];
  __shared__ alignas(16) float s_h1[4][64];
  const int tid = threadIdx.x;
  for (int i = tid; i < 128 * 64; i += 256) s_w1[i] = w1[i];
  for (int i = tid; i < 64 * 32;  i += 256) s_w2[i] = w2[i];
  if (tid < 32) s_w3[tid] = w3[tid];
  __syncthreads();

  const int t  = tid & 63;
  const int wv = tid >> 6;
  const int nwaves = gridDim.x << 2;
  const float b1t = b1[t];
  const float bb3 = b3[0];
  const int n2 = t & 31;
  const float b2n = b2[n2];
  for (int b = (blockIdx.x << 2) + wv; b < NB; b += nwaves) {
    s_x[wv][t]      = user_vec[(size_t)b * 64 + t];
    s_x[wv][64 + t] = target_rep[(size_t)b * 64 + t];
    float a0 = b1t, a1 = 0.f, a2 = 0.f, a3 = 0.f;
#pragma unroll
    for (int k4 = 0; k4 < 32; ++k4) {
      float4 x = *reinterpret_cast<const float4*>(&s_x[wv][k4 * 4]);
      a0 = fmaf(x.x, s_w1[(4 * k4 + 0) * 64 + t], a0);
      a1 = fmaf(x.y, s_w1[(4 * k4 + 1) * 64 + t], a1);
      a2 = fmaf(x.z, s_w1[(4 * k4 + 2) * 64 + t], a2);
      a3 = fmaf(x.w, s_w1[(4 * k4 + 3) * 64 + t], a3);
    }
    s_h1[wv][t] = fmaxf((a0 + a1) + (a2 + a3), 0.f);
    float c0 = b2n, c1 = 0.f, c2 = 0.f, c3 = 0.f;
#pragma unroll
    for (int k4 = 0; k4 < 16; ++k4) {
      float4 x = *reinterpret_cast<const float4*>(&s_h1[wv][k4 * 4]);
      c0 = fmaf(x.x, s_w2[(4 * k4 + 0) * 32 + n2], c0);
      c1 = fmaf(x.y, s_w2[(4 * k4 + 1) * 32 + n2], c1);
      c2 = fmaf(x.z, s_w2[(4 * k4 + 2) * 32 + n2], c2);
      c3 = fmaf(x.w, s_w2[(4 * k4 + 3) * 32 + n2], c3);
    }
    const float h2 = fmaxf((c0 + c1) + (c2 + c3), 0.f);
    float p = (t < 32) ? h2 * s_w3[n2] : 0.f;
#pragma unroll
    for (int m = 32; m >= 1; m >>= 1) p += __shfl_xor(p, m, 64);
    if (t == 0) out[b] = p + bb3;
  }
}

extern "C" void kernel_launch(void* const* d_in, const int* in_sizes, int n_in,
                              void* d_out, int out_size, void* d_ws, size_t ws_size,
                              hipStream_t stream) {
  const int*   hidx  = (const int*)  d_in[0];
  const float* hfeat = (const float*)d_in[1];
  const float* hrat  = (const float*)d_in[2];
  const int*   tidx  = (const int*)  d_in[3];
  const float* tfeat = (const float*)d_in[4];
  const float* table = (const float*)d_in[5];
  const float* fw    = (const float*)d_in[6];
  const float* fb    = (const float*)d_in[7];
  const float* w1    = (const float*)d_in[8];
  const float* b1    = (const float*)d_in[9];
  const float* w2    = (const float*)d_in[10];
  const float* b2    = (const float*)d_in[11];
  const float* w3    = (const float*)d_in[12];
  const float* b3    = (const float*)d_in[13];
  float* out = (float*)d_out;
  float* ws  = (float*)d_ws;
  unsigned* bfrag   = (unsigned*)ws;      // 8192 dwords
  float* user_vec   = ws + 6400000;
  float* target_rep = ws + 7448576;

  hipLaunchKernelGGL(wprep_k, dim3(32), dim3(256), 0, stream, fw, bfrag);
  hipLaunchKernelGGL(pool_mfma_k, dim3(512), dim3(256), 0, stream,
                     hidx, hfeat, hrat, tidx, tfeat, table, fb, bfrag,
                     user_vec, target_rep);
  hipLaunchKernelGGL(mlp_k, dim3(512), dim3(256), 0, stream,
                     user_vec, target_rep, w1, b1, w2, b2, w3, b3, out);
}

// Round 8
// 118.457 us; speedup vs baseline: 4.5139x; 1.1196x over previous
//
#include <hip/hip_runtime.h>

#define NB 16384
#define NH 50

typedef __attribute__((ext_vector_type(4))) float        f32x4;
typedef __attribute__((ext_vector_type(8))) short        s16x8;
typedef __attribute__((ext_vector_type(4))) unsigned int u32x4;

// ws layout (floats):
//   bfrag (u32) : [0, 8192)        32 KB  — W hi/lo bf16 MFMA fragments
//   user_vec    : [6400000, +1M)   4.2 MB
//   target_rep  : [7448576, +1M)   4.2 MB

__device__ __forceinline__ unsigned rne16(float x) {
  unsigned u = __float_as_uint(x);
  return (u + 0x7FFFu + ((u >> 16) & 1u)) >> 16;
}
__device__ __forceinline__ unsigned pack_hi(float x0, float x1, float& r0, float& r1) {
  const unsigned h0 = rne16(x0), h1 = rne16(x1);
  r0 = x0 - __uint_as_float(h0 << 16);
  r1 = x1 - __uint_as_float(h1 << 16);
  return h0 | (h1 << 16);
}
__device__ __forceinline__ unsigned pack_rne(float x0, float x1) {
  return rne16(x0) | (rne16(x1) << 16);
}
__device__ __forceinline__ void cvt8(const f32x4 a, const f32x4 b, u32x4& hi, u32x4& lo) {
  float r0, r1;
  hi[0] = pack_hi(a[0], a[1], r0, r1); lo[0] = pack_rne(r0, r1);
  hi[1] = pack_hi(a[2], a[3], r0, r1); lo[1] = pack_rne(r0, r1);
  hi[2] = pack_hi(b[0], b[1], r0, r1); lo[2] = pack_rne(r0, r1);
  hi[3] = pack_hi(b[2], b[3], r0, r1); lo[3] = pack_rne(r0, r1);
}

// ---------------- kernel W: build bf16 hi/lo B-fragments of fusion_w ----------------
// frag set f = (ks<<3)|(nt<<1)|sp ; lane l ; dword j : B[ks*32+(l>>4)*8+2j(+1)][nt*16+(l&15)]
__global__ __launch_bounds__(256) void wprep_k(const float* __restrict__ fw,
                                               unsigned* __restrict__ bfrag) {
  const int d = blockIdx.x * 256 + threadIdx.x;   // 0..8191
  const int j = d & 3, l = (d >> 2) & 63, f = d >> 8;
  const int sp = f & 1, nt = (f >> 1) & 3, ks = f >> 3;
  const int n  = nt * 16 + (l & 15);
  const int k0 = ks * 32 + (l >> 4) * 8 + 2 * j;
  const float w0 = fw[k0 * 64 + n], w1 = fw[(k0 + 1) * 64 + n];
  const unsigned h0 = rne16(w0), h1 = rne16(w1);
  unsigned dw;
  if (sp == 0) dw = h0 | (h1 << 16);
  else {
    const float r0 = w0 - __uint_as_float(h0 << 16);
    const float r1 = w1 - __uint_as_float(h1 << 16);
    dw = rne16(r0) | (rne16(r1) << 16);
  }
  bfrag[d] = dw;
}

// ---------------- kernel B: MFMA item-rep + pooling ----------------
// grid 2048 x 256: 8192 waves, 2 batches per wave (b, b+8192).
__global__ __launch_bounds__(256, 2) void pool_mfma_k(
    const int* __restrict__ hidx, const float* __restrict__ hfeat,
    const float* __restrict__ hrat, const int* __restrict__ tidx,
    const float* __restrict__ tfeat, const float* __restrict__ table,
    const float* __restrict__ fb, const unsigned* __restrict__ bfrag,
    float* __restrict__ user_vec, float* __restrict__ target_rep)
{
  const int l  = threadIdx.x & 63;
  const int wv = threadIdx.x >> 6;
  const int wave = (blockIdx.x << 2) + wv;          // 0..8191
  const int lm = l & 15, lg = l >> 4;
  const int b0 = wave, b1 = wave + 8192;

  // --- coalesced headers for BOTH batches, issued before anything else ---
  const int r_l = (l < NH) ? l : (NH - 1);
  int idxv0 = hidx[(size_t)b0 * NH + r_l];
  int idxv1 = hidx[(size_t)b1 * NH + r_l];
  float rat0 = (l < NH) ? (hrat[(size_t)b0 * NH + l] - 3.0f) : 0.f;
  float rat1 = (l < NH) ? (hrat[(size_t)b1 * NH + l] - 3.0f) : 0.f;
  if (l == NH) { idxv0 = tidx[b0]; idxv1 = tidx[b1]; }   // lane 50 carries target

  // W fragments resident in VGPRs for the wave lifetime
  u32x4 B[4][4][2];
#pragma unroll
  for (int ks = 0; ks < 4; ++ks)
#pragma unroll
    for (int nt = 0; nt < 4; ++nt)
#pragma unroll
      for (int sp = 0; sp < 2; ++sp) {
        const int f = (ks << 3) | (nt << 1) | sp;
        B[ks][nt][sp] = *(const u32x4*)(bfrag + ((size_t)f * 64 + l) * 4);
      }
  float bias[4];
#pragma unroll
  for (int nt = 0; nt < 4; ++nt) bias[nt] = fb[nt * 16 + lm];

#pragma unroll
  for (int rep = 0; rep < 2; ++rep) {
    const int   b      = rep ? b1 : b0;
    const int   myidx  = rep ? idxv1 : idxv0;
    const float rw_all = rep ? rat1 : rat0;

    float den = fabsf(rw_all);
#pragma unroll
    for (int s = 32; s >= 1; s >>= 1) den += __shfl_xor(den, s, 64);

    float uacc[4] = {0.f, 0.f, 0.f, 0.f};
    float trep[4] = {0.f, 0.f, 0.f, 0.f};

#pragma unroll
    for (int m = 0; m < 4; ++m) {
      const int r = m * 16 + lm;                    // A-row this lane loads
      const int idxm = __shfl(myidx, (r < NH) ? r : ((r == NH) ? NH : (NH - 1)), 64);
      const float* fp = (r < NH) ? (hfeat + ((size_t)b * NH + r) * 64)
                      : (r == NH) ? (tfeat + (size_t)b * 64)
                                  : (hfeat + ((size_t)b * NH + (NH - 1)) * 64);
      const float* ep = table + (size_t)idxm * 64;
      // A cols: 0..63 = emb (gathered), 64..127 = feat ; lane holds 8 consecutive k per kstep
      f32x4 q0 = *(const f32x4*)(ep + lg * 8);
      f32x4 q1 = *(const f32x4*)(ep + lg * 8 + 4);
      f32x4 q2 = *(const f32x4*)(ep + 32 + lg * 8);
      f32x4 q3 = *(const f32x4*)(ep + 32 + lg * 8 + 4);
      f32x4 q4 = *(const f32x4*)(fp + lg * 8);
      f32x4 q5 = *(const f32x4*)(fp + lg * 8 + 4);
      f32x4 q6 = *(const f32x4*)(fp + 32 + lg * 8);
      f32x4 q7 = *(const f32x4*)(fp + 32 + lg * 8 + 4);
      u32x4 ahi[4], alo[4];
      cvt8(q0, q1, ahi[0], alo[0]);
      cvt8(q2, q3, ahi[1], alo[1]);
      cvt8(q4, q5, ahi[2], alo[2]);
      cvt8(q6, q7, ahi[3], alo[3]);

      f32x4 acc[4];
#pragma unroll
      for (int nt = 0; nt < 4; ++nt) {
        const float bv = bias[nt];
        acc[nt] = (f32x4){bv, bv, bv, bv};
      }
#pragma unroll
      for (int ks = 0; ks < 4; ++ks) {
        const s16x8 ah = __builtin_bit_cast(s16x8, ahi[ks]);
        const s16x8 al = __builtin_bit_cast(s16x8, alo[ks]);
#pragma unroll
        for (int nt = 0; nt < 4; ++nt) {
          const s16x8 bh = __builtin_bit_cast(s16x8, B[ks][nt][0]);
          const s16x8 bl = __builtin_bit_cast(s16x8, B[ks][nt][1]);
          acc[nt] = __builtin_amdgcn_mfma_f32_16x16x32_bf16(ah, bh, acc[nt], 0, 0, 0);
          acc[nt] = __builtin_amdgcn_mfma_f32_16x16x32_bf16(al, bh, acc[nt], 0, 0, 0);
          acc[nt] = __builtin_amdgcn_mfma_f32_16x16x32_bf16(ah, bl, acc[nt], 0, 0, 0);
        }
      }
      // epilogue: relu + weighted pooling ; C layout: col=lm+16nt, row=m*16+lg*4+e
#pragma unroll
      for (int nt = 0; nt < 4; ++nt) {
#pragma unroll
        for (int e = 0; e < 4; ++e) {
          const float repv = fmaxf(acc[nt][e], 0.f);
          const int   rr   = m * 16 + lg * 4 + e;
          const float w    = __shfl(rw_all, rr, 64);
          uacc[nt] = fmaf(w, repv, uacc[nt]);
          if (m == 3 && e == 2) trep[nt] = repv;   // row 50 = target (valid on lg==0)
        }
      }
    }

    // reduce over the 4 row-groups, then lane l writes col l
#pragma unroll
    for (int nt = 0; nt < 4; ++nt) {
      uacc[nt] += __shfl_xor(uacc[nt], 16, 64);
      uacc[nt] += __shfl_xor(uacc[nt], 32, 64);
    }
    const float dinv = den + 1e-8f;
    const float usel = (lg == 0) ? uacc[0] : (lg == 1) ? uacc[1]
                     : (lg == 2) ? uacc[2] : uacc[3];
    user_vec[(size_t)b * 64 + l] = usel / dinv;
    if (l < 16) {
      float* tp = target_rep + (size_t)b * 64 + l;
      tp[0]  = trep[0];
      tp[16] = trep[1];
      tp[32] = trep[2];
      tp[48] = trep[3];
    }
  }
}

// ---------------- kernel C: rating MLP ----------------
__global__ __launch_bounds__(256) void mlp_k(
    const float* __restrict__ user_vec, const float* __restrict__ target_rep,
    const float* __restrict__ w1, const float* __restrict__ b1,
    const float* __restrict__ w2, const float* __restrict__ b2,
    const float* __restrict__ w3, const float* __restrict__ b3,
    float* __restrict__ out)
{
  __shared__ alignas(16) float s_w1[128 * 64];  // 32 KB
  __shared__ alignas(16) float s_w2[64 * 32];   //  8 KB
  __shared__ float s_w3[32];
  __shared__ alignas(16) float s_x[4][128];
  __shared__ alignas(16) float s_h1[4][64];
  const int tid = threadIdx.x;
  for (int i = tid; i < 128 * 64; i += 256) s_w1[i] = w1[i];
  for (int i = tid; i < 64 * 32;  i += 256) s_w2[i] = w2[i];
  if (tid < 32) s_w3[tid] = w3[tid];
  __syncthreads();

  const int t  = tid & 63;
  const int wv = tid >> 6;
  const int nwaves = gridDim.x << 2;
  const float b1t = b1[t];
  const float bb3 = b3[0];
  const int n2 = t & 31;
  const float b2n = b2[n2];
  for (int b = (blockIdx.x << 2) + wv; b < NB; b += nwaves) {
    s_x[wv][t]      = user_vec[(size_t)b * 64 + t];
    s_x[wv][64 + t] = target_rep[(size_t)b * 64 + t];
    float a0 = b1t, a1 = 0.f, a2 = 0.f, a3 = 0.f;
#pragma unroll
    for (int k4 = 0; k4 < 32; ++k4) {
      float4 x = *reinterpret_cast<const float4*>(&s_x[wv][k4 * 4]);
      a0 = fmaf(x.x, s_w1[(4 * k4 + 0) * 64 + t], a0);
      a1 = fmaf(x.y, s_w1[(4 * k4 + 1) * 64 + t], a1);
      a2 = fmaf(x.z, s_w1[(4 * k4 + 2) * 64 + t], a2);
      a3 = fmaf(x.w, s_w1[(4 * k4 + 3) * 64 + t], a3);
    }
    s_h1[wv][t] = fmaxf((a0 + a1) + (a2 + a3), 0.f);
    float c0 = b2n, c1 = 0.f, c2 = 0.f, c3 = 0.f;
#pragma unroll
    for (int k4 = 0; k4 < 16; ++k4) {
      float4 x = *reinterpret_cast<const float4*>(&s_h1[wv][k4 * 4]);
      c0 = fmaf(x.x, s_w2[(4 * k4 + 0) * 32 + n2], c0);
      c1 = fmaf(x.y, s_w2[(4 * k4 + 1) * 32 + n2], c1);
      c2 = fmaf(x.z, s_w2[(4 * k4 + 2) * 32 + n2], c2);
      c3 = fmaf(x.w, s_w2[(4 * k4 + 3) * 32 + n2], c3);
    }
    const float h2 = fmaxf((c0 + c1) + (c2 + c3), 0.f);
    float p = (t < 32) ? h2 * s_w3[n2] : 0.f;
#pragma unroll
    for (int m = 32; m >= 1; m >>= 1) p += __shfl_xor(p, m, 64);
    if (t == 0) out[b] = p + bb3;
  }
}

extern "C" void kernel_launch(void* const* d_in, const int* in_sizes, int n_in,
                              void* d_out, int out_size, void* d_ws, size_t ws_size,
                              hipStream_t stream) {
  const int*   hidx  = (const int*)  d_in[0];
  const float* hfeat = (const float*)d_in[1];
  const float* hrat  = (const float*)d_in[2];
  const int*   tidx  = (const int*)  d_in[3];
  const float* tfeat = (const float*)d_in[4];
  const float* table = (const float*)d_in[5];
  const float* fw    = (const float*)d_in[6];
  const float* fb    = (const float*)d_in[7];
  const float* w1    = (const float*)d_in[8];
  const float* b1    = (const float*)d_in[9];
  const float* w2    = (const float*)d_in[10];
  const float* b2    = (const float*)d_in[11];
  const float* w3    = (const float*)d_in[12];
  const float* b3    = (const float*)d_in[13];
  float* out = (float*)d_out;
  float* ws  = (float*)d_ws;
  unsigned* bfrag   = (unsigned*)ws;      // 8192 dwords
  float* user_vec   = ws + 6400000;
  float* target_rep = ws + 7448576;

  hipLaunchKernelGGL(wprep_k, dim3(32), dim3(256), 0, stream, fw, bfrag);
  hipLaunchKernelGGL(pool_mfma_k, dim3(2048), dim3(256), 0, stream,
                     hidx, hfeat, hrat, tidx, tfeat, table, fb, bfrag,
                     user_vec, target_rep);
  hipLaunchKernelGGL(mlp_k, dim3(512), dim3(256), 0, stream,
                     user_vec, target_rep, w1, b1, w2, b2, w3, b3, out);
}